// Round 12
// baseline (389.610 us; speedup 1.0000x reference)
//
#include <hip/hip_runtime.h>
#include <hip/hip_bf16.h>

#define DIM 128

typedef __bf16 bf16x8 __attribute__((ext_vector_type(8)));
typedef float f32x4 __attribute__((ext_vector_type(4)));

static inline int cdiv(int a, int b) { return (a + b - 1) / b; }
static inline size_t align256(size_t x) { return (x + 255) & ~size_t(255); }

__device__ inline unsigned short f2bf(float f) {
    union { float f; unsigned int u; } v; v.f = f;
    unsigned int r = v.u + 0x7fff + ((v.u >> 16) & 1);   // RNE
    return (unsigned short)(r >> 16);
}
__device__ inline unsigned int hb(float f) {             // half-up bf16, 2 ops
    return (__builtin_bit_cast(unsigned int, f) + 0x8000u) >> 16;
}

// -------- kernel 1: segment offsets via binary search (seg sorted ascending)
__global__ void seg_offsets_kernel(const int* __restrict__ seg, int m, int nseg,
                                   int* __restrict__ off) {
    int s = blockIdx.x * blockDim.x + threadIdx.x;
    if (s > nseg) return;
    int lo = 0, hi = m;
    while (lo < hi) {
        int mid = (lo + hi) >> 1;
        if (seg[mid] < s) lo = mid + 1; else hi = mid;
    }
    off[s] = lo;
}

// -------- kernel 2: fp32 -> bf16 convert (node_x), float4 granularity
__global__ void f32_to_bf16_kernel(const float* __restrict__ in,
                                   unsigned short* __restrict__ out, int n4) {
    int i = blockIdx.x * blockDim.x + threadIdx.x;
    if (i >= n4) return;
    float4 v = ((const float4*)in)[i];
    ushort4 o;
    o.x = f2bf(v.x); o.y = f2bf(v.y); o.z = f2bf(v.z); o.w = f2bf(v.w);
    ((ushort4*)out)[i] = o;
}

// -------- kernel 3: pre-swizzle W (4 matrices of 128x128 fp32) into frag-major bf16.
// Entry e=(t,n,lane): 8 bf16 = W[t*32 + (lane>>4)*8 + j][n*16 + (lane&15)], j=0..7.
__global__ void swizzle_w_kernel(const float* __restrict__ W_e, const float* __restrict__ W_n,
                                 unsigned short* __restrict__ wsw) {
    int gid = blockIdx.x * blockDim.x + threadIdx.x;  // 4 * 2048 threads
    int mi = gid >> 11;
    int e = gid & 2047;
    const float* W = (mi < 2) ? (W_e + (size_t)mi * DIM * DIM)
                              : (W_n + (size_t)(mi - 2) * DIM * DIM);
    int t = e >> 9, n = (e >> 6) & 7, lane = e & 63;
    int q = lane >> 4, c = lane & 15;
    int k0 = t * 32 + q * 8, col = n * 16 + c;
    unsigned short vals[8];
#pragma unroll
    for (int j = 0; j < 8; ++j) vals[j] = f2bf(W[(size_t)(k0 + j) * DIM + col]);
    ushort4* dst = (ushort4*)(wsw + (size_t)gid * 8);
    dst[0] = make_ushort4(vals[0], vals[1], vals[2], vals[3]);
    dst[1] = make_ushort4(vals[4], vals[5], vals[6], vals[7]);
}

// slim accumulate: hi half = direct bitcast (<=1-ulp mantissa noise, absorbed by LN)
__device__ inline void accum8s(float* a, uint4 v, float wt) {
    unsigned int u[4] = {v.x, v.y, v.z, v.w};
#pragma unroll
    for (int i = 0; i < 4; ++i) {
        float lo = __builtin_bit_cast(float, u[i] << 16);
        float hi = __builtin_bit_cast(float, u[i]);
        a[2 * i]     = fmaf(wt, lo, a[2 * i]);
        a[2 * i + 1] = fmaf(wt, hi, a[2 * i + 1]);
    }
}

// -------- kernel 4 v4: FUSED pool + GEMM + LN + ReLU.
// 512 threads = 8 waves; block = 128 segments; wave w owns rows w*16..w*16+15.
// Pooling is PAIR-INTERLEAVED: each quarter-wave pools 2 segments concurrently
// (8 outstanding row loads + 8 map loads) into an XOR-swizzled 32 KB LDS tile.
// W staged in 32 KB LDS once (single barrier), MFMA, slim LN/ReLU epilogue.
__global__ __launch_bounds__(512)
void fused_pool_gemm_ln_relu_v4_kernel(const uint4* __restrict__ src,
                                       const int* __restrict__ map,
                                       const int* __restrict__ off,
                                       const unsigned short* __restrict__ Wsw,
                                       const float* __restrict__ b,
                                       const float* __restrict__ g,
                                       const float* __restrict__ be,
                                       unsigned short* __restrict__ Y,
                                       int nseg, int M) {
    __shared__ bf16x8 wlds[2048];              // 32 KB, frag-major W
    __shared__ unsigned short alds[128 * 128]; // 32 KB pooled A-tile, XOR-swizzled
    int tid = threadIdx.x;
    int w = tid >> 6, lane = tid & 63;
    int q = lane >> 4, c = lane & 15;

    {   // stage swizzled W (global layout == LDS layout)
        const uint4* gsrc = (const uint4*)Wsw;
        uint4* ldst = (uint4*)wlds;
#pragma unroll
        for (int i = 0; i < 4; ++i) ldst[tid + i * 512] = gsrc[tid + i * 512];
    }

    int blockbase = blockIdx.x * 128;
    int wavebase = w * 16;

    // epilogue params + hoisted segment boundaries (independent early loads)
    float bcol[8], gcol[8], becol[8];
#pragma unroll
    for (int n = 0; n < 8; ++n) {
        int col = n * 16 + c;
        bcol[n] = b[col]; gcol[n] = g[col]; becol[n] = be[col];
    }
    // quarter q owns local rows {2q, 2q+1, 8+2q, 9+2q}
    int rloc[4] = {2 * q, 2 * q + 1, 8 + 2 * q, 9 + 2 * q};
    int begv[4], endv[4];
#pragma unroll
    for (int k = 0; k < 4; ++k) {
        int sc = min(blockbase + wavebase + rloc[k], nseg - 1);
        begv[k] = off[sc];
        endv[k] = off[sc + 1];
    }

    __syncthreads();   // W visible to all waves

    // ---- phase 1: pair-interleaved pooling (2 segments per quarter concurrently)
#pragma unroll
    for (int p = 0; p < 2; ++p) {
        int kA = 2 * p, kB = 2 * p + 1;
        int begA = begv[kA], endA = endv[kA];
        int begB = begv[kB], endB = endv[kB];
        int safeA = min(begA, M - 1), safeB = min(begB, M - 1);
        int iters = max((endA - begA + 3) >> 2, (endB - begB + 3) >> 2);
        float aA[8] = {0.f, 0.f, 0.f, 0.f, 0.f, 0.f, 0.f, 0.f};
        float aB[8] = {0.f, 0.f, 0.f, 0.f, 0.f, 0.f, 0.f, 0.f};
        int jA = begA, jB = begB;
        for (int i = 0; i < iters; ++i) {
            int ia[4], ib[4];
            float wa[4], wb[4];
#pragma unroll
            for (int k = 0; k < 4; ++k) {
                int t = jA + k;
                ia[k] = (t < endA) ? t : safeA;
                wa[k] = (t < endA) ? 1.f : 0.f;
                t = jB + k;
                ib[k] = (t < endB) ? t : safeB;
                wb[k] = (t < endB) ? 1.f : 0.f;
            }
            int rA0 = map[ia[0]], rA1 = map[ia[1]], rA2 = map[ia[2]], rA3 = map[ia[3]];
            int rB0 = map[ib[0]], rB1 = map[ib[1]], rB2 = map[ib[2]], rB3 = map[ib[3]];
            uint4 vA0 = src[(size_t)rA0 * 16 + c];
            uint4 vA1 = src[(size_t)rA1 * 16 + c];
            uint4 vA2 = src[(size_t)rA2 * 16 + c];
            uint4 vA3 = src[(size_t)rA3 * 16 + c];
            uint4 vB0 = src[(size_t)rB0 * 16 + c];
            uint4 vB1 = src[(size_t)rB1 * 16 + c];
            uint4 vB2 = src[(size_t)rB2 * 16 + c];
            uint4 vB3 = src[(size_t)rB3 * 16 + c];
            accum8s(aA, vA0, wa[0]); accum8s(aA, vA1, wa[1]);
            accum8s(aA, vA2, wa[2]); accum8s(aA, vA3, wa[3]);
            accum8s(aB, vB0, wb[0]); accum8s(aB, vB1, wb[1]);
            accum8s(aB, vB2, wb[2]); accum8s(aB, vB3, wb[3]);
            jA += 4; jB += 4;
        }
        float invA = 1.f / fmaxf((float)(endA - begA), 1.f);
        float invB = 1.f / fmaxf((float)(endB - begB), 1.f);
        int sA = wavebase + rloc[kA], sB = wavebase + rloc[kB];
        uint4 oA, oB;
        oA.x = hb(aA[0] * invA) | (hb(aA[1] * invA) << 16);
        oA.y = hb(aA[2] * invA) | (hb(aA[3] * invA) << 16);
        oA.z = hb(aA[4] * invA) | (hb(aA[5] * invA) << 16);
        oA.w = hb(aA[6] * invA) | (hb(aA[7] * invA) << 16);
        oB.x = hb(aB[0] * invB) | (hb(aB[1] * invB) << 16);
        oB.y = hb(aB[2] * invB) | (hb(aB[3] * invB) << 16);
        oB.z = hb(aB[4] * invB) | (hb(aB[5] * invB) << 16);
        oB.w = hb(aB[6] * invB) | (hb(aB[7] * invB) << 16);
        ((uint4*)(alds + (size_t)sA * 128))[c ^ (sA & 7)] = oA;
        ((uint4*)(alds + (size_t)sB * 128))[c ^ (sB & 7)] = oB;
    }

    // bias-seeded accumulator
    f32x4 acc[8];
#pragma unroll
    for (int n = 0; n < 8; ++n) acc[n] = f32x4{bcol[n], bcol[n], bcol[n], bcol[n]};

    // ---- phase 2: GEMM from own LDS rows (wave-local ds ordering; no barrier)
    const uint4* arow = (const uint4*)(alds + (size_t)(wavebase + c) * 128);
    int key = c & 7;   // (wavebase+c)&7 == c&7
    bf16x8 a0 = *(const bf16x8*)&arow[(q + 0) ^ key];
    bf16x8 a1 = *(const bf16x8*)&arow[(q + 4) ^ key];
    bf16x8 a2 = *(const bf16x8*)&arow[(q + 8) ^ key];
    bf16x8 a3 = *(const bf16x8*)&arow[(q + 12) ^ key];

#pragma unroll
    for (int n = 0; n < 8; ++n) {
        acc[n] = __builtin_amdgcn_mfma_f32_16x16x32_bf16(a0, wlds[(0 * 8 + n) * 64 + lane], acc[n], 0, 0, 0);
        acc[n] = __builtin_amdgcn_mfma_f32_16x16x32_bf16(a1, wlds[(1 * 8 + n) * 64 + lane], acc[n], 0, 0, 0);
        acc[n] = __builtin_amdgcn_mfma_f32_16x16x32_bf16(a2, wlds[(2 * 8 + n) * 64 + lane], acc[n], 0, 0, 0);
        acc[n] = __builtin_amdgcn_mfma_f32_16x16x32_bf16(a3, wlds[(3 * 8 + n) * 64 + lane], acc[n], 0, 0, 0);
    }

    // LN sums per row (lane's rows: blockbase + wavebase + q*4 + j, col n*16+c)
    float s1[4], s2[4];
#pragma unroll
    for (int j = 0; j < 4; ++j) {
        float t1 = 0.f, t2 = 0.f;
#pragma unroll
        for (int n = 0; n < 8; ++n) { float v = acc[n][j]; t1 += v; t2 = fmaf(v, v, t2); }
        s1[j] = t1; s2[j] = t2;
    }
#pragma unroll
    for (int o = 1; o < 16; o <<= 1)
#pragma unroll
        for (int j = 0; j < 4; ++j) {
            s1[j] += __shfl_xor(s1[j], o);
            s2[j] += __shfl_xor(s2[j], o);
        }

#pragma unroll
    for (int j = 0; j < 4; ++j) {
        int row = blockbase + wavebase + q * 4 + j;
        if (row >= nseg) continue;
        float m = s1[j] * (1.f / DIM);
        float var = fmaf(-m, m, s2[j] * (1.f / DIM));
        float inv = rsqrtf(var + 1e-5f);
        unsigned short* yp = Y + (size_t)row * DIM + c;
#pragma unroll
        for (int n = 0; n < 8; ++n) {
            float d = acc[n][j] - m;
            float y = fmaxf(fmaf(d * inv, gcol[n], becol[n]), 0.f);
            unsigned int u = __builtin_bit_cast(unsigned int, y) + 0x8000u;  // half-up
            yp[n * 16] = (unsigned short)(u >> 16);   // -> global_store_short_d16_hi
        }
    }
}

// -------- kernel 5: classifier + log_softmax, quarter-wave per row, 4 rows/quarter.
#define CL_ROWS 4
__global__ __launch_bounds__(256)
void classifier_logsoftmax_v3_kernel(const uint4* __restrict__ X,
                                     const float* __restrict__ Wc,
                                     const float* __restrict__ bc,
                                     float* __restrict__ out, int nrows) {
    int w = threadIdx.x >> 6, lane = threadIdx.x & 63;
    int g = lane >> 4, c16 = lane & 15;
    int r0 = (blockIdx.x * 16 + w * 4 + g) * CL_ROWS;
    if (r0 >= nrows) return;

    float wc[8][10];
#pragma unroll
    for (int j = 0; j < 8; ++j)
#pragma unroll
        for (int c = 0; c < 10; ++c) wc[j][c] = Wc[(c16 * 8 + j) * 10 + c];
    float bcv[10];
#pragma unroll
    for (int c = 0; c < 10; ++c) bcv[c] = bc[c];

    int rend = min(r0 + CL_ROWS, nrows);
    for (int r = r0; r < rend; ++r) {
        uint4 v = X[(size_t)r * 16 + c16];
        float x[8];
        {
            unsigned int u[4] = {v.x, v.y, v.z, v.w};
#pragma unroll
            for (int i = 0; i < 4; ++i) {
                union { unsigned int ui; float f; } lo, hi;
                lo.ui = u[i] << 16;
                hi.ui = u[i] & 0xffff0000u;
                x[2 * i] = lo.f; x[2 * i + 1] = hi.f;
            }
        }
        float acc[10];
#pragma unroll
        for (int c = 0; c < 10; ++c) acc[c] = 0.f;
#pragma unroll
        for (int j = 0; j < 8; ++j)
#pragma unroll
            for (int c = 0; c < 10; ++c) acc[c] = fmaf(x[j], wc[j][c], acc[c]);

#pragma unroll
        for (int o = 1; o < 16; o <<= 1)
#pragma unroll
            for (int c = 0; c < 10; ++c) acc[c] += __shfl_xor(acc[c], o);

#pragma unroll
        for (int c = 0; c < 10; ++c) acc[c] += bcv[c];

        float mx = acc[0];
#pragma unroll
        for (int c = 1; c < 10; ++c) mx = fmaxf(mx, acc[c]);
        float se = 0.f;
#pragma unroll
        for (int c = 0; c < 10; ++c) se += expf(acc[c] - mx);
        float lse = mx + logf(se);

        float myv = 0.f;
#pragma unroll
        for (int c = 0; c < 10; ++c) myv = (c16 == c) ? acc[c] : myv;
        if (c16 < 10) out[(size_t)r * 10 + c16] = myv - lse;
    }
}

extern "C" void kernel_launch(void* const* d_in, const int* in_sizes, int n_in,
                              void* d_out, int out_size, void* d_ws, size_t ws_size,
                              hipStream_t stream) {
    const float* node_x    = (const float*)d_in[0];
    const int*   nodes_map = (const int*)d_in[1];
    const int*   edge_seg  = (const int*)d_in[2];
    const int*   edges_map = (const int*)d_in[3];
    const int*   node_seg  = (const int*)d_in[4];
    const float* W_e = (const float*)d_in[6];
    const float* b_e = (const float*)d_in[7];
    const float* g_e = (const float*)d_in[8];
    const float* be_e= (const float*)d_in[9];
    const float* W_n = (const float*)d_in[10];
    const float* b_n = (const float*)d_in[11];
    const float* g_n = (const float*)d_in[12];
    const float* be_n= (const float*)d_in[13];
    const float* W_c = (const float*)d_in[14];
    const float* b_c = (const float*)d_in[15];
    float* out = (float*)d_out;

    const int N = in_sizes[0] / DIM;           // 100000
    const int M = in_sizes[1];                 // 800000
    const int E = 200000;                      // N_EDGES (problem constant)
    const int L = in_sizes[6] / (DIM * DIM);   // 2

    // workspace carve-up
    char* ws = (char*)d_ws;
    int* edge_off = (int*)ws;           ws += align256((size_t)(E + 1) * sizeof(int));
    int* node_off = (int*)ws;           ws += align256((size_t)(N + 1) * sizeof(int));
    unsigned short* wsw = (unsigned short*)ws;      ws += align256((size_t)4 * 2048 * 8 * sizeof(unsigned short));
    unsigned short* node_xb = (unsigned short*)ws;  ws += align256((size_t)N * DIM * sizeof(unsigned short));
    unsigned short* exb = (unsigned short*)ws;      ws += align256((size_t)E * DIM * sizeof(unsigned short));
    unsigned short* xb  = (unsigned short*)ws;      ws += align256((size_t)N * DIM * sizeof(unsigned short));
    (void)ws_size;

    seg_offsets_kernel<<<cdiv(E + 1, 256), 256, 0, stream>>>(edge_seg, M, E, edge_off);
    seg_offsets_kernel<<<cdiv(N + 1, 256), 256, 0, stream>>>(node_seg, M, N, node_off);
    f32_to_bf16_kernel<<<cdiv(N * DIM / 4, 256), 256, 0, stream>>>(node_x, node_xb, N * DIM / 4);
    swizzle_w_kernel<<<32, 256, 0, stream>>>(W_e, W_n, wsw);

    const unsigned short* xcur = node_xb;
    for (int i = 0; i < L; ++i) {
        // N2E: pool node rows per hyperedge, then edge-MLP
        fused_pool_gemm_ln_relu_v4_kernel<<<cdiv(E, 128), 512, 0, stream>>>(
            (const uint4*)xcur, nodes_map, edge_off, wsw + (size_t)i * 16384,
            b_e + i * DIM, g_e + i * DIM, be_e + i * DIM, exb, E, M);
        // E2N: pool edge rows per node, then node-MLP
        fused_pool_gemm_ln_relu_v4_kernel<<<cdiv(N, 128), 512, 0, stream>>>(
            (const uint4*)exb, edges_map, node_off, wsw + (size_t)(2 + i) * 16384,
            b_n + i * DIM, g_n + i * DIM, be_n + i * DIM, xb, N, M);
        xcur = xb;
    }

    classifier_logsoftmax_v3_kernel<<<cdiv(N, 16 * CL_ROWS), 256, 0, stream>>>(
        (const uint4*)xcur, W_c, b_c, out, N);
}

// Round 13
// 349.434 us; speedup vs baseline: 1.1150x; 1.1150x over previous
//
#include <hip/hip_runtime.h>
#include <hip/hip_bf16.h>

#define DIM 128

typedef __bf16 bf16x8 __attribute__((ext_vector_type(8)));
typedef float f32x4 __attribute__((ext_vector_type(4)));

static inline int cdiv(int a, int b) { return (a + b - 1) / b; }
static inline size_t align256(size_t x) { return (x + 255) & ~size_t(255); }

__device__ inline unsigned short f2bf(float f) {
    union { float f; unsigned int u; } v; v.f = f;
    unsigned int r = v.u + 0x7fff + ((v.u >> 16) & 1);   // RNE
    return (unsigned short)(r >> 16);
}
__device__ inline unsigned int hb(float f) {             // half-up bf16, 2 ops
    return (__builtin_bit_cast(unsigned int, f) + 0x8000u) >> 16;
}

// -------- kernel 1: segment offsets via binary search (seg sorted ascending)
__global__ void seg_offsets_kernel(const int* __restrict__ seg, int m, int nseg,
                                   int* __restrict__ off) {
    int s = blockIdx.x * blockDim.x + threadIdx.x;
    if (s > nseg) return;
    int lo = 0, hi = m;
    while (lo < hi) {
        int mid = (lo + hi) >> 1;
        if (seg[mid] < s) lo = mid + 1; else hi = mid;
    }
    off[s] = lo;
}

// -------- kernel 2: fp32 -> bf16 convert (node_x), float4 granularity
__global__ void f32_to_bf16_kernel(const float* __restrict__ in,
                                   unsigned short* __restrict__ out, int n4) {
    int i = blockIdx.x * blockDim.x + threadIdx.x;
    if (i >= n4) return;
    float4 v = ((const float4*)in)[i];
    ushort4 o;
    o.x = f2bf(v.x); o.y = f2bf(v.y); o.z = f2bf(v.z); o.w = f2bf(v.w);
    ((ushort4*)out)[i] = o;
}

// -------- kernel 3: pre-swizzle W (4 matrices of 128x128 fp32) into frag-major bf16.
// Entry e=(t,n,lane): 8 bf16 = W[t*32 + (lane>>4)*8 + j][n*16 + (lane&15)], j=0..7.
__global__ void swizzle_w_kernel(const float* __restrict__ W_e, const float* __restrict__ W_n,
                                 unsigned short* __restrict__ wsw) {
    int gid = blockIdx.x * blockDim.x + threadIdx.x;  // 4 * 2048 threads
    int mi = gid >> 11;
    int e = gid & 2047;
    const float* W = (mi < 2) ? (W_e + (size_t)mi * DIM * DIM)
                              : (W_n + (size_t)(mi - 2) * DIM * DIM);
    int t = e >> 9, n = (e >> 6) & 7, lane = e & 63;
    int q = lane >> 4, c = lane & 15;
    int k0 = t * 32 + q * 8, col = n * 16 + c;
    unsigned short vals[8];
#pragma unroll
    for (int j = 0; j < 8; ++j) vals[j] = f2bf(W[(size_t)(k0 + j) * DIM + col]);
    ushort4* dst = (ushort4*)(wsw + (size_t)gid * 8);
    dst[0] = make_ushort4(vals[0], vals[1], vals[2], vals[3]);
    dst[1] = make_ushort4(vals[4], vals[5], vals[6], vals[7]);
}

// slim accumulate: 3 VALU/uint. hi half = direct bitcast (<=1-ulp mantissa noise,
// absorbed by LN; validated R11/R12 — absmax unchanged at 0.015625)
__device__ inline void accum8s(float* a, uint4 v, float wt) {
    unsigned int u[4] = {v.x, v.y, v.z, v.w};
#pragma unroll
    for (int i = 0; i < 4; ++i) {
        float lo = __builtin_bit_cast(float, u[i] << 16);
        float hi = __builtin_bit_cast(float, u[i]);
        a[2 * i]     = fmaf(wt, lo, a[2 * i]);
        a[2 * i + 1] = fmaf(wt, hi, a[2 * i + 1]);
    }
}

// -------- kernel 4 v5: FUSED pool + GEMM + LN + ReLU (v2 structure + VALU diet).
// 512 threads = 8 waves; block = 128 segments; wave w owns rows w*16..w*16+15:
// pools them (quarter per segment, 4 each, 4-deep row pipeline) into an
// XOR-swizzled 32 KB LDS tile, then MFMAs those same rows — no barrier between
// pool and GEMM (wave-local ds ordering). Single __syncthreads after W staging.
// Gather loads use 32-bit byte offsets (uniform base + voffset addressing).
__global__ __launch_bounds__(512)
void fused_pool_gemm_ln_relu_v5_kernel(const uint4* __restrict__ src,
                                       const int* __restrict__ map,
                                       const int* __restrict__ off,
                                       const unsigned short* __restrict__ Wsw,
                                       const float* __restrict__ b,
                                       const float* __restrict__ g,
                                       const float* __restrict__ be,
                                       unsigned short* __restrict__ Y,
                                       int nseg) {
    __shared__ bf16x8 wlds[2048];              // 32 KB, frag-major W
    __shared__ unsigned short alds[128 * 128]; // 32 KB pooled A-tile, XOR-swizzled
    int tid = threadIdx.x;
    int w = tid >> 6, lane = tid & 63;
    int q = lane >> 4, c = lane & 15;

    {   // stage swizzled W (global layout == LDS layout)
        const uint4* gsrc = (const uint4*)Wsw;
        uint4* ldst = (uint4*)wlds;
#pragma unroll
        for (int i = 0; i < 4; ++i) ldst[tid + i * 512] = gsrc[tid + i * 512];
    }

    int blockbase = blockIdx.x * 128;
    int wavebase = w * 16;

    // epilogue params + hoisted segment boundaries (independent early loads,
    // issued before the barrier so their latency overlaps W staging)
    float bcol[8], gcol[8], becol[8];
#pragma unroll
    for (int n = 0; n < 8; ++n) {
        int col = n * 16 + c;
        bcol[n] = b[col]; gcol[n] = g[col]; becol[n] = be[col];
    }
    int begv[4], endv[4];
#pragma unroll
    for (int it = 0; it < 4; ++it) {
        int sc = min(blockbase + wavebase + it * 4 + q, nseg - 1);
        begv[it] = off[sc];
        endv[it] = off[sc + 1];
    }

    __syncthreads();   // only barrier: W visible to all waves

    // ---- phase 1: wave pools its own 16 rows (quarter per segment, 4 each)
    const char* sbase = (const char*)src;
    unsigned cb = (unsigned)(c << 4);   // lane's byte offset within a row
    for (int it = 0; it < 4; ++it) {
        int s_local = wavebase + it * 4 + q;
        int beg = begv[it], end = endv[it];
        float a[8] = {0.f, 0.f, 0.f, 0.f, 0.f, 0.f, 0.f, 0.f};
        for (int j = beg; j < end; j += 4) {
            int j1 = min(j + 1, end - 1), j2 = min(j + 2, end - 1), j3 = min(j + 3, end - 1);
            unsigned r0 = (unsigned)map[j], r1 = (unsigned)map[j1];
            unsigned r2 = (unsigned)map[j2], r3 = (unsigned)map[j3];
            // 32-bit byte offsets: (r<<8) + cb  ->  global_load base+voffset
            uint4 v0 = *(const uint4*)(sbase + ((r0 << 8) + cb));
            uint4 v1 = *(const uint4*)(sbase + ((r1 << 8) + cb));
            uint4 v2 = *(const uint4*)(sbase + ((r2 << 8) + cb));
            uint4 v3 = *(const uint4*)(sbase + ((r3 << 8) + cb));
            accum8s(a, v0, 1.f);
            accum8s(a, v1, (j + 1 < end) ? 1.f : 0.f);
            accum8s(a, v2, (j + 2 < end) ? 1.f : 0.f);
            accum8s(a, v3, (j + 3 < end) ? 1.f : 0.f);
        }
        float inv = 1.f / fmaxf((float)(end - beg), 1.f);
        uint4 o;
        o.x = hb(a[0] * inv) | (hb(a[1] * inv) << 16);
        o.y = hb(a[2] * inv) | (hb(a[3] * inv) << 16);
        o.z = hb(a[4] * inv) | (hb(a[5] * inv) << 16);
        o.w = hb(a[6] * inv) | (hb(a[7] * inv) << 16);
        // XOR-swizzled store: row s_local, logical chunk c -> physical c ^ (row&7)
        uint4* wrow = (uint4*)(alds + (size_t)s_local * 128);
        wrow[c ^ (s_local & 7)] = o;
    }

    // bias-seeded accumulator
    f32x4 acc[8];
#pragma unroll
    for (int n = 0; n < 8; ++n) acc[n] = f32x4{bcol[n], bcol[n], bcol[n], bcol[n]};

    // ---- phase 2: GEMM from own LDS rows (ds ordering is wave-local; no barrier)
    const uint4* arow = (const uint4*)(alds + (size_t)(wavebase + c) * 128);
    int key = c & 7;   // (wavebase+c)&7 == c&7
    bf16x8 a0 = *(const bf16x8*)&arow[(q + 0) ^ key];
    bf16x8 a1 = *(const bf16x8*)&arow[(q + 4) ^ key];
    bf16x8 a2 = *(const bf16x8*)&arow[(q + 8) ^ key];
    bf16x8 a3 = *(const bf16x8*)&arow[(q + 12) ^ key];

#pragma unroll
    for (int n = 0; n < 8; ++n) {
        acc[n] = __builtin_amdgcn_mfma_f32_16x16x32_bf16(a0, wlds[(0 * 8 + n) * 64 + lane], acc[n], 0, 0, 0);
        acc[n] = __builtin_amdgcn_mfma_f32_16x16x32_bf16(a1, wlds[(1 * 8 + n) * 64 + lane], acc[n], 0, 0, 0);
        acc[n] = __builtin_amdgcn_mfma_f32_16x16x32_bf16(a2, wlds[(2 * 8 + n) * 64 + lane], acc[n], 0, 0, 0);
        acc[n] = __builtin_amdgcn_mfma_f32_16x16x32_bf16(a3, wlds[(3 * 8 + n) * 64 + lane], acc[n], 0, 0, 0);
    }

    // LN sums per row (lane's rows: blockbase + wavebase + q*4 + j, col n*16+c)
    float s1[4], s2[4];
#pragma unroll
    for (int j = 0; j < 4; ++j) {
        float t1 = 0.f, t2 = 0.f;
#pragma unroll
        for (int n = 0; n < 8; ++n) { float v = acc[n][j]; t1 += v; t2 = fmaf(v, v, t2); }
        s1[j] = t1; s2[j] = t2;
    }
#pragma unroll
    for (int o = 1; o < 16; o <<= 1)
#pragma unroll
        for (int j = 0; j < 4; ++j) {
            s1[j] += __shfl_xor(s1[j], o);
            s2[j] += __shfl_xor(s2[j], o);
        }

#pragma unroll
    for (int j = 0; j < 4; ++j) {
        int row = blockbase + wavebase + q * 4 + j;
        if (row >= nseg) continue;
        float m = s1[j] * (1.f / DIM);
        float var = fmaf(-m, m, s2[j] * (1.f / DIM));
        float inv = rsqrtf(var + 1e-5f);
        unsigned short* yp = Y + (size_t)row * DIM + c;
#pragma unroll
        for (int n = 0; n < 8; ++n) {
            float d = acc[n][j] - m;
            float y = fmaxf(fmaf(d * inv, gcol[n], becol[n]), 0.f);
            unsigned int u = __builtin_bit_cast(unsigned int, y) + 0x8000u;  // half-up
            yp[n * 16] = (unsigned short)(u >> 16);   // -> global_store_short_d16_hi
        }
    }
}

// -------- kernel 5: classifier + log_softmax, quarter-wave per row, 4 rows/quarter.
#define CL_ROWS 4
__global__ __launch_bounds__(256)
void classifier_logsoftmax_v3_kernel(const uint4* __restrict__ X,
                                     const float* __restrict__ Wc,
                                     const float* __restrict__ bc,
                                     float* __restrict__ out, int nrows) {
    int w = threadIdx.x >> 6, lane = threadIdx.x & 63;
    int g = lane >> 4, c16 = lane & 15;
    int r0 = (blockIdx.x * 16 + w * 4 + g) * CL_ROWS;
    if (r0 >= nrows) return;

    float wc[8][10];
#pragma unroll
    for (int j = 0; j < 8; ++j)
#pragma unroll
        for (int c = 0; c < 10; ++c) wc[j][c] = Wc[(c16 * 8 + j) * 10 + c];
    float bcv[10];
#pragma unroll
    for (int c = 0; c < 10; ++c) bcv[c] = bc[c];

    int rend = min(r0 + CL_ROWS, nrows);
    for (int r = r0; r < rend; ++r) {
        uint4 v = X[(size_t)r * 16 + c16];
        float x[8];
        {
            unsigned int u[4] = {v.x, v.y, v.z, v.w};
#pragma unroll
            for (int i = 0; i < 4; ++i) {
                union { unsigned int ui; float f; } lo, hi;
                lo.ui = u[i] << 16;
                hi.ui = u[i] & 0xffff0000u;
                x[2 * i] = lo.f; x[2 * i + 1] = hi.f;
            }
        }
        float acc[10];
#pragma unroll
        for (int c = 0; c < 10; ++c) acc[c] = 0.f;
#pragma unroll
        for (int j = 0; j < 8; ++j)
#pragma unroll
            for (int c = 0; c < 10; ++c) acc[c] = fmaf(x[j], wc[j][c], acc[c]);

#pragma unroll
        for (int o = 1; o < 16; o <<= 1)
#pragma unroll
            for (int c = 0; c < 10; ++c) acc[c] += __shfl_xor(acc[c], o);

#pragma unroll
        for (int c = 0; c < 10; ++c) acc[c] += bcv[c];

        float mx = acc[0];
#pragma unroll
        for (int c = 1; c < 10; ++c) mx = fmaxf(mx, acc[c]);
        float se = 0.f;
#pragma unroll
        for (int c = 0; c < 10; ++c) se += expf(acc[c] - mx);
        float lse = mx + logf(se);

        float myv = 0.f;
#pragma unroll
        for (int c = 0; c < 10; ++c) myv = (c16 == c) ? acc[c] : myv;
        if (c16 < 10) out[(size_t)r * 10 + c16] = myv - lse;
    }
}

extern "C" void kernel_launch(void* const* d_in, const int* in_sizes, int n_in,
                              void* d_out, int out_size, void* d_ws, size_t ws_size,
                              hipStream_t stream) {
    const float* node_x    = (const float*)d_in[0];
    const int*   nodes_map = (const int*)d_in[1];
    const int*   edge_seg  = (const int*)d_in[2];
    const int*   edges_map = (const int*)d_in[3];
    const int*   node_seg  = (const int*)d_in[4];
    const float* W_e = (const float*)d_in[6];
    const float* b_e = (const float*)d_in[7];
    const float* g_e = (const float*)d_in[8];
    const float* be_e= (const float*)d_in[9];
    const float* W_n = (const float*)d_in[10];
    const float* b_n = (const float*)d_in[11];
    const float* g_n = (const float*)d_in[12];
    const float* be_n= (const float*)d_in[13];
    const float* W_c = (const float*)d_in[14];
    const float* b_c = (const float*)d_in[15];
    float* out = (float*)d_out;

    const int N = in_sizes[0] / DIM;           // 100000
    const int M = in_sizes[1];                 // 800000
    const int E = 200000;                      // N_EDGES (problem constant)
    const int L = in_sizes[6] / (DIM * DIM);   // 2

    // workspace carve-up
    char* ws = (char*)d_ws;
    int* edge_off = (int*)ws;           ws += align256((size_t)(E + 1) * sizeof(int));
    int* node_off = (int*)ws;           ws += align256((size_t)(N + 1) * sizeof(int));
    unsigned short* wsw = (unsigned short*)ws;      ws += align256((size_t)4 * 2048 * 8 * sizeof(unsigned short));
    unsigned short* node_xb = (unsigned short*)ws;  ws += align256((size_t)N * DIM * sizeof(unsigned short));
    unsigned short* exb = (unsigned short*)ws;      ws += align256((size_t)E * DIM * sizeof(unsigned short));
    unsigned short* xb  = (unsigned short*)ws;      ws += align256((size_t)N * DIM * sizeof(unsigned short));
    (void)ws_size;

    seg_offsets_kernel<<<cdiv(E + 1, 256), 256, 0, stream>>>(edge_seg, M, E, edge_off);
    seg_offsets_kernel<<<cdiv(N + 1, 256), 256, 0, stream>>>(node_seg, M, N, node_off);
    f32_to_bf16_kernel<<<cdiv(N * DIM / 4, 256), 256, 0, stream>>>(node_x, node_xb, N * DIM / 4);
    swizzle_w_kernel<<<32, 256, 0, stream>>>(W_e, W_n, wsw);

    const unsigned short* xcur = node_xb;
    for (int i = 0; i < L; ++i) {
        // N2E: pool node rows per hyperedge, then edge-MLP
        fused_pool_gemm_ln_relu_v5_kernel<<<cdiv(E, 128), 512, 0, stream>>>(
            (const uint4*)xcur, nodes_map, edge_off, wsw + (size_t)i * 16384,
            b_e + i * DIM, g_e + i * DIM, be_e + i * DIM, exb, E);
        // E2N: pool edge rows per node, then node-MLP
        fused_pool_gemm_ln_relu_v5_kernel<<<cdiv(N, 128), 512, 0, stream>>>(
            (const uint4*)exb, edges_map, node_off, wsw + (size_t)(2 + i) * 16384,
            b_n + i * DIM, g_n + i * DIM, be_n + i * DIM, xb, N);
        xcur = xb;
    }

    classifier_logsoftmax_v3_kernel<<<cdiv(N, 16 * CL_ROWS), 256, 0, stream>>>(
        (const uint4*)xcur, W_c, b_c, out, N);
}